// Round 3
// baseline (1128.421 us; speedup 1.0000x reference)
//
#include <hip/hip_runtime.h>

typedef unsigned short u16;
typedef unsigned int   u32;
typedef __bf16 bf16x8 __attribute__((ext_vector_type(8)));
typedef float  f32x4  __attribute__((ext_vector_type(4)));
typedef float  f32x16 __attribute__((ext_vector_type(16)));

__device__ __forceinline__ u16 f2bf(float f){
  u32 u = __float_as_uint(f);
  u32 r = (u + 0x7FFFu + ((u >> 16) & 1u)) >> 16;   // RNE
  return (u16)r;
}

// ---------------------------------------------------------------------------
// Pass 1: row sums of A (f32) fused with A -> bf16 conversion (unscaled).
// ---------------------------------------------------------------------------
__global__ __launch_bounds__(256) void rowsum_convert(
    const float* __restrict__ A, u16* __restrict__ Ab, float* __restrict__ ds){
  const int row = blockIdx.x, t = threadIdx.x;
  const float* ar = A + (size_t)row * 8192;
  u16* br = Ab + (size_t)row * 8192;
  float s = 0.f;
  #pragma unroll
  for (int j = 0; j < 8; ++j){
    int c = j * 256 + t;                    // float4 index, coalesced
    float4 v = ((const float4*)ar)[c];
    s += (v.x + v.y) + (v.z + v.w);
    ushort4 o;
    o.x = f2bf(v.x); o.y = f2bf(v.y); o.z = f2bf(v.z); o.w = f2bf(v.w);
    ((ushort4*)br)[c] = o;
  }
  #pragma unroll
  for (int off = 32; off > 0; off >>= 1) s += __shfl_down(s, off, 64);
  __shared__ float red[4];
  if ((t & 63) == 0) red[t >> 6] = s;
  __syncthreads();
  if (t == 0) ds[row] = rsqrtf(red[0] + red[1] + red[2] + red[3]);
}

// ---------------------------------------------------------------------------
// Small feature GEMM: Vt[o][i] = bf16( ds[i] * sum_k in[i][k] * W[k][o] )
// ---------------------------------------------------------------------------
template<int K, int F, bool INBF16>
__global__ __launch_bounds__(256) void small_gemm(
    const void* __restrict__ inp, const float* __restrict__ W,
    const float* __restrict__ ds, u16* __restrict__ Vt){
  constexpr int G   = 256 / F;     // 1 (F=256) or 2 (F=128)
  constexpr int RPB = 16 * G;      // rows per block
  __shared__ float xs[RPB * K];
  const int t  = threadIdx.x;
  const int r0 = blockIdx.x * RPB;
  if constexpr (INBF16){
    const u16* ip = (const u16*)inp + (size_t)r0 * K;
    constexpr int IT = (RPB * K) / (256 * 8);
    #pragma unroll
    for (int j = 0; j < IT; ++j){
      int c = j * 256 + t;
      uint4 v = ((const uint4*)ip)[c];
      float* xp = xs + c * 8;
      xp[0] = __uint_as_float((v.x & 0xFFFFu) << 16);
      xp[1] = __uint_as_float(v.x & 0xFFFF0000u);
      xp[2] = __uint_as_float((v.y & 0xFFFFu) << 16);
      xp[3] = __uint_as_float(v.y & 0xFFFF0000u);
      xp[4] = __uint_as_float((v.z & 0xFFFFu) << 16);
      xp[5] = __uint_as_float(v.z & 0xFFFF0000u);
      xp[6] = __uint_as_float((v.w & 0xFFFFu) << 16);
      xp[7] = __uint_as_float(v.w & 0xFFFF0000u);
    }
  } else {
    const float* ip = (const float*)inp + (size_t)r0 * K;
    constexpr int IT = (RPB * K) / (256 * 4);
    #pragma unroll
    for (int j = 0; j < IT; ++j){
      int c = j * 256 + t;
      ((float4*)xs)[c] = ((const float4*)ip)[c];
    }
  }
  __syncthreads();
  const int o = t % F, g = t / F;
  float acc[16];
  #pragma unroll
  for (int r = 0; r < 16; ++r) acc[r] = 0.f;
  const float* xr = xs + g * 16 * K;
  for (int k = 0; k < K; k += 4){
    float w0 = W[(k+0)*F + o];
    float w1 = W[(k+1)*F + o];
    float w2 = W[(k+2)*F + o];
    float w3 = W[(k+3)*F + o];
    #pragma unroll
    for (int r = 0; r < 16; ++r){
      float4 xv = *(const float4*)(xr + r*K + k);
      acc[r] += xv.x*w0 + xv.y*w1 + xv.z*w2 + xv.w*w3;
    }
  }
  const int rb = r0 + g * 16;
  union { u16 u[16]; uint4 v[2]; } pk;
  #pragma unroll
  for (int r = 0; r < 16; ++r) pk.u[r] = f2bf(acc[r] * ds[rb + r]);
  uint4* dst = (uint4*)(Vt + (size_t)o * 8192 + rb);
  dst[0] = pk.v[0];
  dst[1] = pk.v[1];
}

// ---------------------------------------------------------------------------
// Big GEMM: register-direct, zero LDS, K-split partials to global f32.
// part[ks][i][o] = sum_{j in slice ks} Ab[i][j] * Vt[o][j]
//
// Per-wave tile 32x32 via mfma_f32_32x32x16_bf16 (1 MFMA + 2x16B loads per
// K-16 step). Block = 64 rows x F cols (WR=2 row-subs x WC=F/32 col-subs).
// <=64 VGPR + 0 LDS -> 32 waves/CU: latency hidden by TLP, not barriers.
// ---------------------------------------------------------------------------
template<int F, int KS>
__global__ __launch_bounds__((F / 32) * 2 * 64, 8) void gemm_big(
    const u16* __restrict__ Ab, const u16* __restrict__ Vt,
    float* __restrict__ part){
  constexpr int WC     = F / 32;        // col-subs per block (8 or 4)
  constexpr int NROWG  = 8192 / 64;     // 128 row-groups
  constexpr int KSLICE = 8192 / KS;
  constexpr int NKT    = KSLICE / 16;   // K-16 steps per slice
  constexpr int D      = 4;             // register prefetch depth

  const int bid  = blockIdx.x;
  const int ks   = bid / NROWG;         // ks slowest: machine phases per slice
  const int rowg = bid % NROWG;
  const int t = threadIdx.x, wave = t >> 6, lane = t & 63;
  const int wr = wave / WC, wc = wave % WC;
  const int row0 = rowg * 64 + wr * 32;
  const int col0 = wc * 32;
  const int kbase = ks * KSLICE + ((lane >> 5) << 3);

  const u16* ap = Ab + (size_t)(row0 + (lane & 31)) * 8192 + kbase;
  const u16* bp = Vt + (size_t)(col0 + (lane & 31)) * 8192 + kbase;

  f32x16 acc;
  #pragma unroll
  for (int i = 0; i < 16; ++i) acc[i] = 0.f;

  bf16x8 aP[D], bP[D];
  #pragma unroll
  for (int d = 0; d < D; ++d){
    aP[d] = *(const bf16x8*)(const void*)(ap + d * 16);
    bP[d] = *(const bf16x8*)(const void*)(bp + d * 16);
  }
  for (int kt = 0; kt < NKT - D; kt += D){
    #pragma unroll
    for (int u = 0; u < D; ++u){
      bf16x8 a = aP[u], b = bP[u];
      aP[u] = *(const bf16x8*)(const void*)(ap + (kt + u + D) * 16);
      bP[u] = *(const bf16x8*)(const void*)(bp + (kt + u + D) * 16);
      acc = __builtin_amdgcn_mfma_f32_32x32x16_bf16(a, b, acc, 0, 0, 0);
    }
  }
  #pragma unroll
  for (int u = 0; u < D; ++u)
    acc = __builtin_amdgcn_mfma_f32_32x32x16_bf16(aP[u], bP[u], acc, 0, 0, 0);

  // C/D layout (m74/m101): col = lane&31, row = (r&3) + 8*(r>>2) + 4*(lane>>5)
  float* pp = part + ((size_t)ks * 8192 + row0) * F + col0 + (lane & 31);
  const int rhi = (lane >> 5) << 2;
  #pragma unroll
  for (int r = 0; r < 16; ++r){
    const int rl = (r & 3) + ((r >> 2) << 3) + rhi;
    pp[(size_t)rl * F] = acc[r];
  }
}

// ---------------------------------------------------------------------------
// K-split reduction + ds scale (+relu / bf16-pack or f32 out).
// ---------------------------------------------------------------------------
template<int F, int KS, bool RELU, bool OUTF32>
__global__ __launch_bounds__(256) void reduce_part(
    const float* __restrict__ part, const float* __restrict__ ds,
    u16* __restrict__ Hout, float* __restrict__ Fout){
  const int g = blockIdx.x * 256 + threadIdx.x;       // float4 group
  constexpr int SL = 8192 * F / 4;                    // slice stride in float4
  const float4* p = (const float4*)part;
  float4 s = p[g];
  #pragma unroll
  for (int k = 1; k < KS; ++k){
    float4 v = p[(size_t)k * SL + g];
    s.x += v.x; s.y += v.y; s.z += v.z; s.w += v.w;
  }
  const int row = g / (F / 4);
  const float d = ds[row];
  s.x *= d; s.y *= d; s.z *= d; s.w *= d;
  if (RELU){
    s.x = fmaxf(s.x, 0.f); s.y = fmaxf(s.y, 0.f);
    s.z = fmaxf(s.z, 0.f); s.w = fmaxf(s.w, 0.f);
  }
  if (OUTF32){
    ((float4*)Fout)[g] = s;
  } else {
    ushort4 o;
    o.x = f2bf(s.x); o.y = f2bf(s.y); o.z = f2bf(s.z); o.w = f2bf(s.w);
    ((ushort4*)Hout)[g] = o;
  }
}

// ---------------------------------------------------------------------------
// Attention scores: sc[i] = tanh(Z[i,:] @ Wl^T + bl) @ q + b
// ---------------------------------------------------------------------------
__device__ __forceinline__ float tanh_fast(float x){
  x = fminf(fmaxf(x, -15.f), 15.f);
  float e = __expf(2.f * x);
  return (e - 1.f) / (e + 1.f);
}

__global__ __launch_bounds__(256) void attn_scores(
    const float* __restrict__ Z, const float* __restrict__ Wl,
    const float* __restrict__ bl, const float* __restrict__ q,
    const float* __restrict__ bsc, float* __restrict__ sc){
  __shared__ float wl[128 * 128];          // 64 KiB exactly, swizzled
  const int t = threadIdx.x, lane = t & 63, wave = t >> 6;
  for (int j = 0; j < 64; ++j){
    int idx = j * 256 + t;
    int o = idx >> 7, k = idx & 127;
    int c = k >> 2, e = k & 3;
    wl[o * 128 + (((c ^ (o & 31)) << 2) | e)] = Wl[idx];
  }
  __syncthreads();
  const float bl0 = bl[lane], bl1 = bl[lane + 64];
  const float q0  = q[lane],  q1  = q[lane + 64];
  const float bb  = bsc[0];
  const int r0 = blockIdx.x * 16;
  for (int rr = 0; rr < 4; ++rr){
    int r = r0 + wave * 4 + rr;
    float d0 = 0.f, d1 = 0.f;
    #pragma unroll
    for (int c = 0; c < 32; ++c){
      float4 zv = *(const float4*)(Z + (size_t)r * 128 + c * 4);
      float4 w0 = *(const float4*)&wl[ lane      * 128 + ((c ^ (lane & 31)) << 2)];
      float4 w1 = *(const float4*)&wl[(lane + 64)* 128 + ((c ^ (lane & 31)) << 2)];
      d0 += zv.x*w0.x + zv.y*w0.y + zv.z*w0.z + zv.w*w0.w;
      d1 += zv.x*w1.x + zv.y*w1.y + zv.z*w1.z + zv.w*w1.w;
    }
    float s = tanh_fast(d0 + bl0) * q0 + tanh_fast(d1 + bl1) * q1;
    #pragma unroll
    for (int off = 32; off > 0; off >>= 1) s += __shfl_down(s, off, 64);
    if (lane == 0) sc[r] = s + bb;
  }
}

__global__ __launch_bounds__(1024) void softmax_red(
    const float* __restrict__ sc, float* __restrict__ sred){
  const int t = threadIdx.x, lane = t & 63, wave = t >> 6;
  __shared__ float red[16];
  float m = -1e30f;
  for (int i = t; i < 8192; i += 1024) m = fmaxf(m, sc[i]);
  #pragma unroll
  for (int off = 32; off > 0; off >>= 1) m = fmaxf(m, __shfl_down(m, off, 64));
  if (lane == 0) red[wave] = m;
  __syncthreads();
  if (t == 0){
    float mm = red[0];
    for (int w = 1; w < 16; ++w) mm = fmaxf(mm, red[w]);
    red[0] = mm;
  }
  __syncthreads();
  const float bmax = red[0];
  __syncthreads();
  float s = 0.f;
  for (int i = t; i < 8192; i += 1024) s += __expf(sc[i] - bmax);
  #pragma unroll
  for (int off = 32; off > 0; off >>= 1) s += __shfl_down(s, off, 64);
  if (lane == 0) red[wave] = s;
  __syncthreads();
  if (t == 0){
    float ss = 0.f;
    for (int w = 0; w < 16; ++w) ss += red[w];
    sred[0] = bmax; sred[1] = ss;
  }
}

__global__ __launch_bounds__(256) void weighted_part(
    const float* __restrict__ sc, const float* __restrict__ sred,
    const float* __restrict__ Z, float* __restrict__ part){
  const int blk = blockIdx.x, t = threadIdx.x;
  const int o = t & 127, h = t >> 7;
  const float bmax = sred[0], inv = 1.f / sred[1];
  float acc = 0.f;
  const int i0 = blk * 128;
  for (int i = i0 + h; i < i0 + 128; i += 2){
    float w = __expf(sc[i] - bmax) * inv;
    acc += w * Z[(size_t)i * 128 + o];
  }
  __shared__ float l[256];
  l[t] = acc;
  __syncthreads();
  if (h == 0) part[blk * 128 + o] = l[o] + l[o + 128];
}

__global__ __launch_bounds__(128) void final_red(
    const float* __restrict__ part, float* __restrict__ out){
  const int o = threadIdx.x;
  float s = 0.f;
  for (int b = 0; b < 64; ++b) s += part[b * 128 + o];
  out[o] = s;
}

// ---------------------------------------------------------------------------
template<int KS256, int KS128>
static void run_pipeline(const float* x, const float* A, const float* W1,
                         const float* W2, const float* W3, const float* Wl,
                         const float* bl, const float* q, const float* b,
                         float* out, char* ws, hipStream_t stream){
  u16*   AB   = (u16*)(ws);                      // 128 MiB
  float* DS   = (float*)(ws + 134217728);        // 32 KiB
  u16*   VT   = (u16*)(ws + 134250496);          // 4 MiB
  u16*   HB   = (u16*)(ws + 138444800);          // 4 MiB
  float* PART = (float*)(ws + 142639104);        // KS256*8 MiB
  constexpr size_t PB = (size_t)KS256 * 8192 * 256 * 4;
  float* SC   = (float*)(ws + 142639104 + PB);
  float* SP   = (float*)(ws + 142639104 + PB + 32768);
  float* SRED = (float*)(ws + 142639104 + PB + 65536);

  rowsum_convert<<<8192, 256, 0, stream>>>(A, AB, DS);
  // layer 1
  small_gemm<128, 256, false><<<512, 256, 0, stream>>>(x, W1, DS, VT);
  gemm_big<256, KS256><<<128 * KS256, 1024, 0, stream>>>(AB, VT, PART);
  reduce_part<256, KS256, true, false><<<2048, 256, 0, stream>>>(PART, DS, HB, nullptr);
  // layer 2
  small_gemm<256, 256, true><<<512, 256, 0, stream>>>(HB, W2, DS, VT);
  gemm_big<256, KS256><<<128 * KS256, 1024, 0, stream>>>(AB, VT, PART);
  reduce_part<256, KS256, true, false><<<2048, 256, 0, stream>>>(PART, DS, HB, nullptr);
  // layer 3 -> z_context f32 into d_out
  small_gemm<256, 128, true><<<256, 256, 0, stream>>>(HB, W3, DS, VT);
  gemm_big<128, KS128><<<128 * KS128, 512, 0, stream>>>(AB, VT, PART);
  reduce_part<128, KS128, false, true><<<1024, 256, 0, stream>>>(PART, DS, nullptr, out);
  // attention pooling
  attn_scores<<<512, 256, 0, stream>>>(out, Wl, bl, q, b, SC);
  softmax_red<<<1, 1024, 0, stream>>>(SC, SRED);
  weighted_part<<<64, 256, 0, stream>>>(SC, SRED, out, SP);
  final_red<<<1, 128, 0, stream>>>(SP, out + 8192 * 128);
}

extern "C" void kernel_launch(void* const* d_in, const int* in_sizes, int n_in,
                              void* d_out, int out_size, void* d_ws, size_t ws_size,
                              hipStream_t stream){
  const float* x  = (const float*)d_in[0];
  const float* A  = (const float*)d_in[1];
  const float* W1 = (const float*)d_in[2];
  const float* W2 = (const float*)d_in[3];
  const float* W3 = (const float*)d_in[4];
  const float* Wl = (const float*)d_in[5];
  const float* bl = (const float*)d_in[6];
  const float* q  = (const float*)d_in[7];
  const float* b  = (const float*)d_in[8];
  float* out = (float*)d_out;
  char* ws = (char*)d_ws;

  const size_t base = 142639104 + 131072;        // fixed buffers + tails
  if      (ws_size >= base + 33554432) run_pipeline<4, 8>(x, A, W1, W2, W3, Wl, bl, q, b, out, ws, stream);
  else if (ws_size >= base + 16777216) run_pipeline<2, 4>(x, A, W1, W2, W3, Wl, bl, q, b, out, ws, stream);
  else                                 run_pipeline<1, 2>(x, A, W1, W2, W3, Wl, bl, q, b, out, ws, stream);
}

// Round 4
// 740.220 us; speedup vs baseline: 1.5244x; 1.5244x over previous
//
#include <hip/hip_runtime.h>

typedef unsigned short u16;
typedef unsigned int   u32;
typedef __bf16 bf16x8 __attribute__((ext_vector_type(8)));
typedef float  f32x4  __attribute__((ext_vector_type(4)));
typedef float  f32x16 __attribute__((ext_vector_type(16)));

__device__ __forceinline__ u16 f2bf(float f){
  u32 u = __float_as_uint(f);
  u32 r = (u + 0x7FFFu + ((u >> 16) & 1u)) >> 16;   // RNE
  return (u16)r;
}

// ---------------------------------------------------------------------------
// Pass 1: row sums of A (f32) fused with A -> bf16 conversion (unscaled).
// ---------------------------------------------------------------------------
__global__ __launch_bounds__(256) void rowsum_convert(
    const float* __restrict__ A, u16* __restrict__ Ab, float* __restrict__ ds){
  const int row = blockIdx.x, t = threadIdx.x;
  const float* ar = A + (size_t)row * 8192;
  u16* br = Ab + (size_t)row * 8192;
  float s = 0.f;
  #pragma unroll
  for (int j = 0; j < 8; ++j){
    int c = j * 256 + t;                    // float4 index, coalesced
    float4 v = ((const float4*)ar)[c];
    s += (v.x + v.y) + (v.z + v.w);
    ushort4 o;
    o.x = f2bf(v.x); o.y = f2bf(v.y); o.z = f2bf(v.z); o.w = f2bf(v.w);
    ((ushort4*)br)[c] = o;
  }
  #pragma unroll
  for (int off = 32; off > 0; off >>= 1) s += __shfl_down(s, off, 64);
  __shared__ float red[4];
  if ((t & 63) == 0) red[t >> 6] = s;
  __syncthreads();
  if (t == 0) ds[row] = rsqrtf(red[0] + red[1] + red[2] + red[3]);
}

// ---------------------------------------------------------------------------
// Small feature GEMM: Vt[o][i] = bf16( ds[i] * sum_k in[i][k] * W[k][o] )
// ---------------------------------------------------------------------------
template<int K, int F, bool INBF16>
__global__ __launch_bounds__(256) void small_gemm(
    const void* __restrict__ inp, const float* __restrict__ W,
    const float* __restrict__ ds, u16* __restrict__ Vt){
  constexpr int G   = 256 / F;     // 1 (F=256) or 2 (F=128)
  constexpr int RPB = 16 * G;      // rows per block
  __shared__ float xs[RPB * K];
  const int t  = threadIdx.x;
  const int r0 = blockIdx.x * RPB;
  if constexpr (INBF16){
    const u16* ip = (const u16*)inp + (size_t)r0 * K;
    constexpr int IT = (RPB * K) / (256 * 8);
    #pragma unroll
    for (int j = 0; j < IT; ++j){
      int c = j * 256 + t;
      uint4 v = ((const uint4*)ip)[c];
      float* xp = xs + c * 8;
      xp[0] = __uint_as_float((v.x & 0xFFFFu) << 16);
      xp[1] = __uint_as_float(v.x & 0xFFFF0000u);
      xp[2] = __uint_as_float((v.y & 0xFFFFu) << 16);
      xp[3] = __uint_as_float(v.y & 0xFFFF0000u);
      xp[4] = __uint_as_float((v.z & 0xFFFFu) << 16);
      xp[5] = __uint_as_float(v.z & 0xFFFF0000u);
      xp[6] = __uint_as_float((v.w & 0xFFFFu) << 16);
      xp[7] = __uint_as_float(v.w & 0xFFFF0000u);
    }
  } else {
    const float* ip = (const float*)inp + (size_t)r0 * K;
    constexpr int IT = (RPB * K) / (256 * 4);
    #pragma unroll
    for (int j = 0; j < IT; ++j){
      int c = j * 256 + t;
      ((float4*)xs)[c] = ((const float4*)ip)[c];
    }
  }
  __syncthreads();
  const int o = t % F, g = t / F;
  float acc[16];
  #pragma unroll
  for (int r = 0; r < 16; ++r) acc[r] = 0.f;
  const float* xr = xs + g * 16 * K;
  for (int k = 0; k < K; k += 4){
    float w0 = W[(k+0)*F + o];
    float w1 = W[(k+1)*F + o];
    float w2 = W[(k+2)*F + o];
    float w3 = W[(k+3)*F + o];
    #pragma unroll
    for (int r = 0; r < 16; ++r){
      float4 xv = *(const float4*)(xr + r*K + k);
      acc[r] += xv.x*w0 + xv.y*w1 + xv.z*w2 + xv.w*w3;
    }
  }
  const int rb = r0 + g * 16;
  union { u16 u[16]; uint4 v[2]; } pk;
  #pragma unroll
  for (int r = 0; r < 16; ++r) pk.u[r] = f2bf(acc[r] * ds[rb + r]);
  uint4* dst = (uint4*)(Vt + (size_t)o * 8192 + rb);
  dst[0] = pk.v[0];
  dst[1] = pk.v[1];
}

// ---------------------------------------------------------------------------
// Big GEMM: in-block K-split, register-direct K-loop (no barriers), LDS tree
// reduction at the end only.  out[i][o] = ds[i]*sum_j Ab[i][j]*Vt[o][j]
//
// 256 blocks x 1024 threads = 16 waves = 4 K-splits x 4 col-groups.
// Block = 32 rows x F cols (A read ONCE per GEMM = 128 MB; B L2/L3-resident).
// Wave = 32 x F/4 via mfma_f32_32x32x16_bf16; depth-4 register prefetch.
// VGPR ~110 -> 4 waves/SIMD (16 waves/CU); latency hidden by TLP + ILP.
// ---------------------------------------------------------------------------
template<int F, bool RELU, bool OUTF32>
__global__ __launch_bounds__(1024, 4) void gemm_tree(
    const u16* __restrict__ Ab, const u16* __restrict__ Vt,
    const float* __restrict__ ds, u16* __restrict__ Hout, float* __restrict__ Fout){
  constexpr int CT  = F / 128;          // 32-col tiles per wave (2 or 1)
  constexpr int NKT = 2048 / 16;        // 128 K-16 steps per K-split
  constexpr int D   = 4;                // prefetch depth (steps)
  __shared__ float red[2][32][F];       // 64 KB (F=256) / 32 KB (F=128)

  const int t = threadIdx.x, wave = t >> 6, lane = t & 63;
  const int ks = wave >> 2;             // K-split 0..3
  const int cg = wave & 3;              // col-group 0..3
  const int row0 = blockIdx.x * 32;
  const int colb = cg * (F / 4);
  const int kbase = ks * 2048 + ((lane >> 5) << 3);

  const u16* ap = Ab + (size_t)(row0 + (lane & 31)) * 8192 + kbase;
  const u16* bp[CT];
  #pragma unroll
  for (int ct = 0; ct < CT; ++ct)
    bp[ct] = Vt + (size_t)(colb + ct * 32 + (lane & 31)) * 8192 + kbase;

  f32x16 acc[CT];
  #pragma unroll
  for (int ct = 0; ct < CT; ++ct)
    #pragma unroll
    for (int i = 0; i < 16; ++i) acc[ct][i] = 0.f;

  bf16x8 aQ[D], bQ[D][CT];
  #pragma unroll
  for (int d = 0; d < D; ++d){
    aQ[d] = *(const bf16x8*)(const void*)(ap + d * 16);
    #pragma unroll
    for (int ct = 0; ct < CT; ++ct)
      bQ[d][ct] = *(const bf16x8*)(const void*)(bp[ct] + d * 16);
  }
  for (int kt = 0; kt < NKT - D; kt += D){
    #pragma unroll
    for (int u = 0; u < D; ++u){
      bf16x8 a = aQ[u];
      aQ[u] = *(const bf16x8*)(const void*)(ap + (kt + u + D) * 16);
      #pragma unroll
      for (int ct = 0; ct < CT; ++ct){
        bf16x8 b = bQ[u][ct];
        bQ[u][ct] = *(const bf16x8*)(const void*)(bp[ct] + (kt + u + D) * 16);
        acc[ct] = __builtin_amdgcn_mfma_f32_32x32x16_bf16(a, b, acc[ct], 0, 0, 0);
      }
    }
  }
  #pragma unroll
  for (int u = 0; u < D; ++u)
    #pragma unroll
    for (int ct = 0; ct < CT; ++ct)
      acc[ct] = __builtin_amdgcn_mfma_f32_32x32x16_bf16(aQ[u], bQ[u][ct], acc[ct], 0, 0, 0);

  // ---- K-split tree reduction: ((ks0+ks2)+(ks1+ks3)), 3 barriers total ----
  // C/D layout (m74/m101): col = lane&31, row = (r&3) + 8*(r>>2) + 4*(lane>>5)
  const int rhi = (lane >> 5) << 2;
  const int cl  = lane & 31;
  if (ks >= 2){                          // ks2 -> red[0], ks3 -> red[1]
    #pragma unroll
    for (int ct = 0; ct < CT; ++ct)
      #pragma unroll
      for (int r = 0; r < 16; ++r)
        red[ks - 2][(r & 3) + ((r >> 2) << 3) + rhi][colb + ct * 32 + cl] = acc[ct][r];
  }
  __syncthreads();
  if (ks < 2){                           // ks0 += red[0], ks1 += red[1]
    #pragma unroll
    for (int ct = 0; ct < CT; ++ct)
      #pragma unroll
      for (int r = 0; r < 16; ++r)
        acc[ct][r] += red[ks][(r & 3) + ((r >> 2) << 3) + rhi][colb + ct * 32 + cl];
  }
  __syncthreads();
  if (ks == 1){                          // ks1 -> red[0]
    #pragma unroll
    for (int ct = 0; ct < CT; ++ct)
      #pragma unroll
      for (int r = 0; r < 16; ++r)
        red[0][(r & 3) + ((r >> 2) << 3) + rhi][colb + ct * 32 + cl] = acc[ct][r];
  }
  __syncthreads();
  if (ks == 0){                          // final: += , scale, (relu), store
    #pragma unroll
    for (int ct = 0; ct < CT; ++ct){
      #pragma unroll
      for (int r = 0; r < 16; ++r){
        const int rl = (r & 3) + ((r >> 2) << 3) + rhi;
        float v = acc[ct][r] + red[0][rl][colb + ct * 32 + cl];
        const int row = row0 + rl;
        v *= ds[row];
        if (RELU) v = fmaxf(v, 0.f);
        const int col = colb + ct * 32 + cl;
        if (OUTF32) Fout[(size_t)row * F + col] = v;
        else        Hout[(size_t)row * F + col] = f2bf(v);
      }
    }
  }
}

// ---------------------------------------------------------------------------
// Attention scores: sc[i] = tanh(Z[i,:] @ Wl^T + bl) @ q + b
// ---------------------------------------------------------------------------
__device__ __forceinline__ float tanh_fast(float x){
  x = fminf(fmaxf(x, -15.f), 15.f);
  float e = __expf(2.f * x);
  return (e - 1.f) / (e + 1.f);
}

__global__ __launch_bounds__(256) void attn_scores(
    const float* __restrict__ Z, const float* __restrict__ Wl,
    const float* __restrict__ bl, const float* __restrict__ q,
    const float* __restrict__ bsc, float* __restrict__ sc){
  __shared__ float wl[128 * 128];          // 64 KiB exactly, swizzled
  const int t = threadIdx.x, lane = t & 63, wave = t >> 6;
  for (int j = 0; j < 64; ++j){
    int idx = j * 256 + t;
    int o = idx >> 7, k = idx & 127;
    int c = k >> 2, e = k & 3;
    wl[o * 128 + (((c ^ (o & 31)) << 2) | e)] = Wl[idx];
  }
  __syncthreads();
  const float bl0 = bl[lane], bl1 = bl[lane + 64];
  const float q0  = q[lane],  q1  = q[lane + 64];
  const float bb  = bsc[0];
  const int r0 = blockIdx.x * 16;
  for (int rr = 0; rr < 4; ++rr){
    int r = r0 + wave * 4 + rr;
    float d0 = 0.f, d1 = 0.f;
    #pragma unroll
    for (int c = 0; c < 32; ++c){
      float4 zv = *(const float4*)(Z + (size_t)r * 128 + c * 4);
      float4 w0 = *(const float4*)&wl[ lane      * 128 + ((c ^ (lane & 31)) << 2)];
      float4 w1 = *(const float4*)&wl[(lane + 64)* 128 + ((c ^ (lane & 31)) << 2)];
      d0 += zv.x*w0.x + zv.y*w0.y + zv.z*w0.z + zv.w*w0.w;
      d1 += zv.x*w1.x + zv.y*w1.y + zv.z*w1.z + zv.w*w1.w;
    }
    float s = tanh_fast(d0 + bl0) * q0 + tanh_fast(d1 + bl1) * q1;
    #pragma unroll
    for (int off = 32; off > 0; off >>= 1) s += __shfl_down(s, off, 64);
    if (lane == 0) sc[r] = s + bb;
  }
}

__global__ __launch_bounds__(1024) void softmax_red(
    const float* __restrict__ sc, float* __restrict__ sred){
  const int t = threadIdx.x, lane = t & 63, wave = t >> 6;
  __shared__ float red[16];
  float m = -1e30f;
  for (int i = t; i < 8192; i += 1024) m = fmaxf(m, sc[i]);
  #pragma unroll
  for (int off = 32; off > 0; off >>= 1) m = fmaxf(m, __shfl_down(m, off, 64));
  if (lane == 0) red[wave] = m;
  __syncthreads();
  if (t == 0){
    float mm = red[0];
    for (int w = 1; w < 16; ++w) mm = fmaxf(mm, red[w]);
    red[0] = mm;
  }
  __syncthreads();
  const float bmax = red[0];
  __syncthreads();
  float s = 0.f;
  for (int i = t; i < 8192; i += 1024) s += __expf(sc[i] - bmax);
  #pragma unroll
  for (int off = 32; off > 0; off >>= 1) s += __shfl_down(s, off, 64);
  if (lane == 0) red[wave] = s;
  __syncthreads();
  if (t == 0){
    float ss = 0.f;
    for (int w = 0; w < 16; ++w) ss += red[w];
    sred[0] = bmax; sred[1] = ss;
  }
}

__global__ __launch_bounds__(256) void weighted_part(
    const float* __restrict__ sc, const float* __restrict__ sred,
    const float* __restrict__ Z, float* __restrict__ part){
  const int blk = blockIdx.x, t = threadIdx.x;
  const int o = t & 127, h = t >> 7;
  const float bmax = sred[0], inv = 1.f / sred[1];
  float acc = 0.f;
  const int i0 = blk * 128;
  for (int i = i0 + h; i < i0 + 128; i += 2){
    float w = __expf(sc[i] - bmax) * inv;
    acc += w * Z[(size_t)i * 128 + o];
  }
  __shared__ float l[256];
  l[t] = acc;
  __syncthreads();
  if (h == 0) part[blk * 128 + o] = l[o] + l[o + 128];
}

__global__ __launch_bounds__(128) void final_red(
    const float* __restrict__ part, float* __restrict__ out){
  const int o = threadIdx.x;
  float s = 0.f;
  for (int b = 0; b < 64; ++b) s += part[b * 128 + o];
  out[o] = s;
}

// ---------------------------------------------------------------------------
extern "C" void kernel_launch(void* const* d_in, const int* in_sizes, int n_in,
                              void* d_out, int out_size, void* d_ws, size_t ws_size,
                              hipStream_t stream){
  const float* x  = (const float*)d_in[0];
  const float* A  = (const float*)d_in[1];
  const float* W1 = (const float*)d_in[2];
  const float* W2 = (const float*)d_in[3];
  const float* W3 = (const float*)d_in[4];
  const float* Wl = (const float*)d_in[5];
  const float* bl = (const float*)d_in[6];
  const float* q  = (const float*)d_in[7];
  const float* b  = (const float*)d_in[8];
  float* out = (float*)d_out;
  char* ws = (char*)d_ws;

  u16*   AB   = (u16*)(ws);                      // 128 MiB
  float* DS   = (float*)(ws + 134217728);        // 32 KiB
  u16*   VT   = (u16*)(ws + 134250496);          // 4 MiB [F][8192]
  u16*   HB   = (u16*)(ws + 138444800);          // 4 MiB [8192][256]
  float* SC   = (float*)(ws + 142639104);        // 8192 f32 scores
  float* SP   = (float*)(ws + 142671872);        // 64*128 f32
  float* SRED = (float*)(ws + 142704640);        // {max, sumexp}

  rowsum_convert<<<8192, 256, 0, stream>>>(A, AB, DS);
  // layer 1
  small_gemm<128, 256, false><<<512, 256, 0, stream>>>(x, W1, DS, VT);
  gemm_tree<256, true, false><<<256, 1024, 0, stream>>>(AB, VT, DS, HB, nullptr);
  // layer 2
  small_gemm<256, 256, true><<<512, 256, 0, stream>>>(HB, W2, DS, VT);
  gemm_tree<256, true, false><<<256, 1024, 0, stream>>>(AB, VT, DS, HB, nullptr);
  // layer 3 -> z_context f32 straight into d_out
  small_gemm<256, 128, true><<<256, 256, 0, stream>>>(HB, W3, DS, VT);
  gemm_tree<128, false, true><<<256, 1024, 0, stream>>>(AB, VT, DS, nullptr, out);
  // attention pooling
  attn_scores<<<512, 256, 0, stream>>>(out, Wl, bl, q, b, SC);
  softmax_red<<<1, 1024, 0, stream>>>(SC, SRED);
  weighted_part<<<64, 256, 0, stream>>>(SC, SRED, out, SP);
  final_red<<<1, 128, 0, stream>>>(SP, out + 8192 * 128);
}